// Round 1
// baseline (421.882 us; speedup 1.0000x reference)
//
#include <hip/hip_runtime.h>
#include <cstdint>
#include <cstddef>

// ---- types ----
typedef _Float16 f16x8 __attribute__((ext_vector_type(8)));
typedef _Float16 f16x4 __attribute__((ext_vector_type(4)));
typedef float    f32x4 __attribute__((ext_vector_type(4)));
typedef unsigned short ushort_t;

#define LOG2E 1.4426950408889634f

constexpr int BATCH = 2;
constexpr int TSEQ  = 2048;
constexpr int HID   = 2048;
constexpr int NH    = 16;
constexpr int HD    = 128;
constexpr int GK    = 2048;   // K-dim of both GEMMs

__device__ inline f32x4 mfma16(f16x8 a, f16x8 b, f32x4 c) {
    return __builtin_amdgcn_mfma_f32_16x16x32_f16(a, b, c, 0, 0, 0);
}

// async global->LDS, 16B per lane; LDS dest must be linear (base + lane*16)
__device__ inline void async_copy16(const void* src, void* dst_lds) {
    __builtin_amdgcn_global_load_lds(
        (const __attribute__((address_space(1))) uint32_t*)src,
        (__attribute__((address_space(3))) uint32_t*)dst_lds, 16, 0, 0);
}

// ---- fp32 -> fp16 cast, vectorized (G13) ----
__global__ __launch_bounds__(256)
void cast_f32_f16(const float4* __restrict__ in, f16x4* __restrict__ out, int n4) {
    int i = blockIdx.x * 256 + threadIdx.x;
    if (i >= n4) return;
    float4 v = in[i];
    f16x4 o = { (_Float16)v.x, (_Float16)v.y, (_Float16)v.z, (_Float16)v.w };
    out[i] = o;
}

// ---- GEMM: C[M,N] = A[M,GK] @ B[N,GK]^T  (both row-major, K contiguous) ----
// MODE 0: N=6144, scatter to Q/K/V [B][NH][T][HD] fp16, Q scaled by 1/sqrt(HD)
// MODE 1: N=2048, write fp32 C[M][2048] (= d_out)
template <int MODE>
__global__ __launch_bounds__(256)
void gemm_bt(const _Float16* __restrict__ A, const _Float16* __restrict__ B,
             float* __restrict__ C, _Float16* __restrict__ Qo,
             _Float16* __restrict__ Ko, _Float16* __restrict__ Vo) {
    __shared__ __align__(16) _Float16 As[128 * 64];
    __shared__ __align__(16) _Float16 Bs[128 * 64];

    const int tid  = threadIdx.x;
    const int lane = tid & 63;
    const int w    = tid >> 6;        // wave 0..3
    const int l15  = lane & 15;
    const int lq   = lane >> 4;
    const int wr   = w >> 1, wc = w & 1;
    const int m0 = blockIdx.y * 128;
    const int n0 = blockIdx.x * 128;

    const _Float16* Ab = A + (size_t)m0 * GK;
    const _Float16* Bb = B + (size_t)n0 * GK;

    const int srow = lane >> 3;        // 0..7
    const int scol = (lane & 7) << 3;  // 0..56

    f32x4 acc[4][4] = {};

    for (int k0 = 0; k0 < GK; k0 += 64) {
        __syncthreads();
        #pragma unroll
        for (int it = 0; it < 4; ++it) {
            const int c   = w * 4 + it;        // 16 chunks of 1KB each
            const int row = c * 8 + srow;      // tile row 0..127
            async_copy16(Ab + (size_t)row * GK + k0 + scol, As + c * 512 + lane * 8);
            async_copy16(Bb + (size_t)row * GK + k0 + scol, Bs + c * 512 + lane * 8);
        }
        __syncthreads();
        #pragma unroll
        for (int kk = 0; kk < 2; ++kk) {
            f16x8 af[4], bfr[4];
            #pragma unroll
            for (int i = 0; i < 4; ++i) {
                af[i]  = *(const f16x8*)(As + (wr * 64 + i * 16 + l15) * 64 + kk * 32 + lq * 8);
                bfr[i] = *(const f16x8*)(Bs + (wc * 64 + i * 16 + l15) * 64 + kk * 32 + lq * 8);
            }
            #pragma unroll
            for (int i = 0; i < 4; ++i)
                #pragma unroll
                for (int j = 0; j < 4; ++j)
                    acc[i][j] = mfma16(af[i], bfr[j], acc[i][j]);
        }
    }

    if (MODE == 0) {
        #pragma unroll
        for (int j = 0; j < 4; ++j) {
            const int ncol = n0 + wc * 64 + j * 16 + l15;
            const int which = ncol >> 11;          // 0=Q 1=K 2=V
            const int oo = ncol & 2047;
            const int head = oo >> 7;
            const int d = oo & 127;
            _Float16* dst = (which == 0) ? Qo : (which == 1) ? Ko : Vo;
            const float scl = (which == 0) ? 0.08838834764831845f : 1.0f;
            #pragma unroll
            for (int i = 0; i < 4; ++i) {
                #pragma unroll
                for (int r = 0; r < 4; ++r) {
                    const int m = m0 + wr * 64 + i * 16 + lq * 4 + r;
                    const int b = m >> 11, t = m & 2047;
                    dst[((size_t)(b * NH + head) * TSEQ + t) * HD + d] =
                        (_Float16)(acc[i][j][r] * scl);
                }
            }
        }
    } else {
        #pragma unroll
        for (int i = 0; i < 4; ++i)
            #pragma unroll
            for (int j = 0; j < 4; ++j)
                #pragma unroll
                for (int r = 0; r < 4; ++r) {
                    const int m = m0 + wr * 64 + i * 16 + lq * 4 + r;
                    const int n = n0 + wc * 64 + j * 16 + l15;
                    C[(size_t)m * HID + n] = acc[i][j][r];
                }
    }
}

// ---- causal flash attention: 64 q-rows/block, 4 waves (16 rows each), KVBLK=64 ----
__global__ __launch_bounds__(256)
void attn_fwd(const _Float16* __restrict__ Q, const _Float16* __restrict__ K,
              const _Float16* __restrict__ V, _Float16* __restrict__ O) {
    __shared__ __align__(16) char Ks[64 * 256];   // [64][128] f16, 16B-block XOR-swizzled
    __shared__ __align__(16) char Vt[128 * 128];  // [128][64] f16 (V^T), XOR-swizzled
    __shared__ __align__(16) char Ps[4][2048];    // per-wave [16][64] f16 P, XOR-swizzled

    const int tid  = threadIdx.x;
    const int lane = tid & 63;
    const int w    = tid >> 6;
    const int l15  = lane & 15;
    const int lq   = lane >> 4;

    const int nqt = TSEQ / 64;                       // 32
    const int qt  = (nqt - 1) - ((int)blockIdx.x % nqt);  // reversed: heavy blocks first
    const int bh  = (int)blockIdx.x / nqt;           // 0..31
    const int b = bh >> 4, h = bh & 15;

    const size_t base = (size_t)bh * TSEQ * HD;
    const _Float16* Qp = Q + base;
    const _Float16* Kp = K + base;
    const _Float16* Vp = V + base;

    const int q0 = qt * 64;
    const int qrow = q0 + w * 16 + l15;   // A-frag row for this lane

    // Q hoisted to registers (pre-scaled by 1/sqrt(HD) in GEMM1 epilogue)
    f16x8 qf[4];
    #pragma unroll
    for (int ks = 0; ks < 4; ++ks)
        qf[ks] = *(const f16x8*)(Qp + (size_t)qrow * HD + ks * 32 + lq * 8);

    f32x4 o[8] = {};
    float m_run[4], l_run[4];
    #pragma unroll
    for (int r = 0; r < 4; ++r) { m_run[r] = -1e30f; l_run[r] = 0.0f; }

    char* Pb = Ps[w];

    for (int kv0 = 0; kv0 <= q0; kv0 += 64) {
        __syncthreads();
        // K -> LDS via global_load_lds; source pre-swizzled so read-side XOR is conflict-free
        #pragma unroll
        for (int it = 0; it < 4; ++it) {
            const int c    = w * 4 + it;
            const int row  = c * 4 + lq;     // 0..63
            const int srcb = l15 ^ (row & 7);
            async_copy16(Kp + (size_t)(kv0 + row) * HD + srcb * 8, Ks + c * 1024 + lane * 16);
        }
        // V -> regs (lane = kv row; conflict-free transposed LDS writes)
        uint4 vv[4];
        #pragma unroll
        for (int it = 0; it < 4; ++it) {
            const int cb = it * 4 + w;
            vv[it] = *(const uint4*)(Vp + (size_t)(kv0 + lane) * HD + cb * 8);
        }
        #pragma unroll
        for (int it = 0; it < 4; ++it) {
            const int cb = it * 4 + w;
            const uint4 t4 = vv[it];
            const uint32_t wrd[4] = {t4.x, t4.y, t4.z, t4.w};
            #pragma unroll
            for (int p2 = 0; p2 < 4; ++p2) {
                const int d0 = cb * 8 + p2 * 2;
                const int d1 = d0 + 1;
                int b0 = d0 * 128 + lane * 2; b0 ^= (d0 & 7) << 4;
                int b1 = d1 * 128 + lane * 2; b1 ^= (d1 & 7) << 4;
                *(ushort_t*)(Vt + b0) = (ushort_t)(wrd[p2] & 0xffffu);
                *(ushort_t*)(Vt + b1) = (ushort_t)(wrd[p2] >> 16);
            }
        }
        __syncthreads();

        // S = Q K^T : D col(lane&15)=kv, row((lane>>4)*4+r)=q
        f32x4 s[4] = {};
        #pragma unroll
        for (int ks = 0; ks < 4; ++ks) {
            #pragma unroll
            for (int nf = 0; nf < 4; ++nf) {
                const int r   = nf * 16 + l15;
                const int blk = (ks * 4 + lq) ^ (r & 7);
                const f16x8 kf = *(const f16x8*)(Ks + r * 256 + blk * 16);
                s[nf] = mfma16(qf[ks], kf, s[nf]);
            }
        }

        if (kv0 == q0) {  // diagonal tile only
            #pragma unroll
            for (int nf = 0; nf < 4; ++nf) {
                const int kvp = nf * 16 + l15;
                #pragma unroll
                for (int r = 0; r < 4; ++r)
                    if (kvp > w * 16 + lq * 4 + r) s[nf][r] = -1e30f;
            }
        }

        // online softmax: row groups = 16 lanes sharing lq
        float alpha[4];
        #pragma unroll
        for (int r = 0; r < 4; ++r) {
            float v = fmaxf(fmaxf(s[0][r], s[1][r]), fmaxf(s[2][r], s[3][r]));
            v = fmaxf(v, __shfl_xor(v, 1));
            v = fmaxf(v, __shfl_xor(v, 2));
            v = fmaxf(v, __shfl_xor(v, 4));
            v = fmaxf(v, __shfl_xor(v, 8));
            const float mn = fmaxf(m_run[r], v);
            alpha[r] = __builtin_exp2f((m_run[r] - mn) * LOG2E);
            m_run[r] = mn;
        }

        float ps[4] = {0.f, 0.f, 0.f, 0.f};
        #pragma unroll
        for (int nf = 0; nf < 4; ++nf) {
            #pragma unroll
            for (int r = 0; r < 4; ++r) {
                const float p = __builtin_exp2f((s[nf][r] - m_run[r]) * LOG2E);
                ps[r] += p;
                const int qp = lq * 4 + r;
                int byt = qp * 128 + (nf * 16 + l15) * 2;
                byt ^= (qp & 7) << 4;
                union { _Float16 hf; ushort_t u; } cv;
                cv.hf = (_Float16)p;
                *(ushort_t*)(Pb + byt) = cv.u;   // wave-private, in-order LDS => no barrier
            }
        }
        #pragma unroll
        for (int r = 0; r < 4; ++r) {
            float v = ps[r];
            v += __shfl_xor(v, 1);
            v += __shfl_xor(v, 2);
            v += __shfl_xor(v, 4);
            v += __shfl_xor(v, 8);
            l_run[r] = l_run[r] * alpha[r] + v;
        }
        #pragma unroll
        for (int df = 0; df < 8; ++df)
            #pragma unroll
            for (int r = 0; r < 4; ++r)
                o[df][r] *= alpha[r];

        // O += P @ V
        #pragma unroll
        for (int ks = 0; ks < 2; ++ks) {
            const int pblk = (ks * 4 + lq) ^ (l15 & 7);
            const f16x8 pf = *(const f16x8*)(Pb + l15 * 128 + pblk * 16);
            #pragma unroll
            for (int df = 0; df < 8; ++df) {
                const int vr   = df * 16 + l15;
                const int vblk = (ks * 4 + lq) ^ (vr & 7);
                const f16x8 vf = *(const f16x8*)(Vt + vr * 128 + vblk * 16);
                o[df] = mfma16(pf, vf, o[df]);
            }
        }
    }

    #pragma unroll
    for (int r = 0; r < 4; ++r) l_run[r] = 1.0f / l_run[r];
    #pragma unroll
    for (int df = 0; df < 8; ++df) {
        #pragma unroll
        for (int r = 0; r < 4; ++r) {
            const int qg = q0 + w * 16 + lq * 4 + r;
            const int dg = df * 16 + l15;
            O[((size_t)(b * TSEQ + qg)) * HID + h * HD + dg] = (_Float16)(o[df][r] * l_run[r]);
        }
    }
}

extern "C" void kernel_launch(void* const* d_in, const int* in_sizes, int n_in,
                              void* d_out, int out_size, void* d_ws, size_t ws_size,
                              hipStream_t stream) {
    (void)in_sizes; (void)n_in; (void)out_size; (void)ws_size;
    const float* hs   = (const float*)d_in[0];
    const float* wqkv = (const float*)d_in[1];
    const float* wout = (const float*)d_in[2];

    // workspace layout (112 MiB total)
    char* ws = (char*)d_ws;
    size_t off = 0;
    _Float16* hs_h   = (_Float16*)(ws + off); off += (size_t)BATCH * TSEQ * HID * 2;
    _Float16* wqkv_h = (_Float16*)(ws + off); off += (size_t)3 * HID * HID * 2;
    _Float16* wout_h = (_Float16*)(ws + off); off += (size_t)HID * HID * 2;
    _Float16* Qh     = (_Float16*)(ws + off); off += (size_t)BATCH * NH * TSEQ * HD * 2;
    _Float16* Kh     = (_Float16*)(ws + off); off += (size_t)BATCH * NH * TSEQ * HD * 2;
    _Float16* Vh     = (_Float16*)(ws + off); off += (size_t)BATCH * NH * TSEQ * HD * 2;
    _Float16* At     = (_Float16*)(ws + off); off += (size_t)BATCH * TSEQ * HID * 2;

    const int n4_hs   = BATCH * TSEQ * HID / 4;
    const int n4_wqkv = 3 * HID * HID / 4;
    const int n4_wout = HID * HID / 4;
    cast_f32_f16<<<dim3((n4_hs   + 255) / 256), dim3(256), 0, stream>>>((const float4*)hs,   (f16x4*)hs_h,   n4_hs);
    cast_f32_f16<<<dim3((n4_wqkv + 255) / 256), dim3(256), 0, stream>>>((const float4*)wqkv, (f16x4*)wqkv_h, n4_wqkv);
    cast_f32_f16<<<dim3((n4_wout + 255) / 256), dim3(256), 0, stream>>>((const float4*)wout, (f16x4*)wout_h, n4_wout);

    gemm_bt<0><<<dim3(3 * HID / 128, BATCH * TSEQ / 128), dim3(256), 0, stream>>>(
        hs_h, wqkv_h, nullptr, Qh, Kh, Vh);

    attn_fwd<<<dim3(BATCH * NH * (TSEQ / 64)), dim3(256), 0, stream>>>(Qh, Kh, Vh, At);

    gemm_bt<1><<<dim3(HID / 128, BATCH * TSEQ / 128), dim3(256), 0, stream>>>(
        At, wout_h, (float*)d_out, nullptr, nullptr, nullptr);
}

// Round 2
// 356.159 us; speedup vs baseline: 1.1845x; 1.1845x over previous
//
#include <hip/hip_runtime.h>
#include <cstdint>
#include <cstddef>

// ---- types ----
typedef _Float16 f16x8 __attribute__((ext_vector_type(8)));
typedef _Float16 f16x4 __attribute__((ext_vector_type(4)));
typedef float    f32x4 __attribute__((ext_vector_type(4)));
typedef unsigned short ushort_t;

#define LOG2E 1.4426950408889634f

constexpr int BATCH = 2;
constexpr int TSEQ  = 2048;
constexpr int HID   = 2048;
constexpr int NH    = 16;
constexpr int HD    = 128;
constexpr int GK    = 2048;   // K-dim of both GEMMs

__device__ inline f32x4 mfma16(f16x8 a, f16x8 b, f32x4 c) {
    return __builtin_amdgcn_mfma_f32_16x16x32_f16(a, b, c, 0, 0, 0);
}

// async global->LDS, 16B per lane; LDS dest must be linear (base + lane*16)
__device__ inline void async_copy16(const void* src, void* dst_lds) {
    __builtin_amdgcn_global_load_lds(
        (const __attribute__((address_space(1))) uint32_t*)src,
        (__attribute__((address_space(3))) uint32_t*)dst_lds, 16, 0, 0);
}

// ---- fp32 -> fp16 cast, vectorized (G13) ----
__global__ __launch_bounds__(256)
void cast_f32_f16(const float4* __restrict__ in, f16x4* __restrict__ out, int n4) {
    int i = blockIdx.x * 256 + threadIdx.x;
    if (i >= n4) return;
    float4 v = in[i];
    f16x4 o = { (_Float16)v.x, (_Float16)v.y, (_Float16)v.z, (_Float16)v.w };
    out[i] = o;
}

// ---- GEMM: C[M,N] = A[M,GK] @ B[N,GK]^T  (both row-major, K contiguous) ----
// MODE 0: N=6144, scatter to Q/K/V [B][NH][T][HD] fp16, Q scaled by 1/sqrt(HD)
// MODE 1: N=2048, write fp32 C[M][2048] (= d_out)
template <int MODE>
__global__ __launch_bounds__(256)
void gemm_bt(const _Float16* __restrict__ A, const _Float16* __restrict__ B,
             float* __restrict__ C, _Float16* __restrict__ Qo,
             _Float16* __restrict__ Ko, _Float16* __restrict__ Vo) {
    __shared__ __align__(16) _Float16 As[128 * 64];
    __shared__ __align__(16) _Float16 Bs[128 * 64];

    const int tid  = threadIdx.x;
    const int lane = tid & 63;
    const int w    = tid >> 6;        // wave 0..3
    const int l15  = lane & 15;
    const int lq   = lane >> 4;
    const int wr   = w >> 1, wc = w & 1;
    const int m0 = blockIdx.y * 128;
    const int n0 = blockIdx.x * 128;

    const _Float16* Ab = A + (size_t)m0 * GK;
    const _Float16* Bb = B + (size_t)n0 * GK;

    const int srow = lane >> 3;        // 0..7
    const int scol = (lane & 7) << 3;  // 0..56

    f32x4 acc[4][4] = {};

    for (int k0 = 0; k0 < GK; k0 += 64) {
        __syncthreads();
        #pragma unroll
        for (int it = 0; it < 4; ++it) {
            const int c   = w * 4 + it;        // 16 chunks of 1KB each
            const int row = c * 8 + srow;      // tile row 0..127
            async_copy16(Ab + (size_t)row * GK + k0 + scol, As + c * 512 + lane * 8);
            async_copy16(Bb + (size_t)row * GK + k0 + scol, Bs + c * 512 + lane * 8);
        }
        __syncthreads();
        #pragma unroll
        for (int kk = 0; kk < 2; ++kk) {
            f16x8 af[4], bfr[4];
            #pragma unroll
            for (int i = 0; i < 4; ++i) {
                af[i]  = *(const f16x8*)(As + (wr * 64 + i * 16 + l15) * 64 + kk * 32 + lq * 8);
                bfr[i] = *(const f16x8*)(Bs + (wc * 64 + i * 16 + l15) * 64 + kk * 32 + lq * 8);
            }
            #pragma unroll
            for (int i = 0; i < 4; ++i)
                #pragma unroll
                for (int j = 0; j < 4; ++j)
                    acc[i][j] = mfma16(af[i], bfr[j], acc[i][j]);
        }
    }

    if (MODE == 0) {
        #pragma unroll
        for (int j = 0; j < 4; ++j) {
            const int ncol = n0 + wc * 64 + j * 16 + l15;
            const int which = ncol >> 11;          // 0=Q 1=K 2=V
            const int oo = ncol & 2047;
            const int head = oo >> 7;
            const int d = oo & 127;
            _Float16* dst = (which == 0) ? Qo : (which == 1) ? Ko : Vo;
            const float scl = (which == 0) ? 0.08838834764831845f : 1.0f;
            #pragma unroll
            for (int i = 0; i < 4; ++i) {
                #pragma unroll
                for (int r = 0; r < 4; ++r) {
                    const int m = m0 + wr * 64 + i * 16 + lq * 4 + r;
                    const int b = m >> 11, t = m & 2047;
                    dst[((size_t)(b * NH + head) * TSEQ + t) * HD + d] =
                        (_Float16)(acc[i][j][r] * scl);
                }
            }
        }
    } else {
        #pragma unroll
        for (int i = 0; i < 4; ++i)
            #pragma unroll
            for (int j = 0; j < 4; ++j)
                #pragma unroll
                for (int r = 0; r < 4; ++r) {
                    const int m = m0 + wr * 64 + i * 16 + lq * 4 + r;
                    const int n = n0 + wc * 64 + j * 16 + l15;
                    C[(size_t)m * HID + n] = acc[i][j][r];
                }
    }
}

// ---- causal flash attention v2 ----
// 512 threads / 8 waves, QBLK=128 q-rows per block (16/wave), KVBLK=64.
// Double-buffered K + V^T LDS, ONE barrier per KV tile (T3 2-phase recipe):
//   writeVt(cur) -> barrier -> issue loads(t+1) -> compute(t)
// Heavy-first dispatch for causal load balance.
__global__ __launch_bounds__(512)
void attn_fwd(const _Float16* __restrict__ Q, const _Float16* __restrict__ K,
              const _Float16* __restrict__ V, _Float16* __restrict__ O) {
    __shared__ __align__(16) char Ks[2][64 * 256];   // [64][128] f16, 16B-block XOR-swizzled
    __shared__ __align__(16) char Vt[2][128 * 128];  // [128][64] f16 (V^T), XOR-swizzled
    __shared__ __align__(16) char Ps[8][2048];       // per-wave [16][64] f16 P, XOR-swizzled

    const int tid  = threadIdx.x;
    const int lane = tid & 63;
    const int w    = tid >> 6;      // 0..7
    const int l15  = lane & 15;
    const int lq   = lane >> 4;

    const int qt = 15 - ((int)blockIdx.x >> 5);   // heavy tiles dispatched first
    const int bh = (int)blockIdx.x & 31;
    const int b = bh >> 4, h = bh & 15;

    const size_t base = (size_t)bh * TSEQ * HD;
    const _Float16* Qp = Q + base;
    const _Float16* Kp = K + base;
    const _Float16* Vp = V + base;

    const int q0 = qt * 128;
    const int NT = 2 * qt + 2;      // KV tiles of 64

    // Q hoisted to registers (pre-scaled by 1/sqrt(HD) in GEMM1 epilogue)
    const int qrow = q0 + w * 16 + l15;
    f16x8 qf[4];
    #pragma unroll
    for (int ks = 0; ks < 4; ++ks)
        qf[ks] = *(const f16x8*)(Qp + (size_t)qrow * HD + ks * 32 + lq * 8);

    f32x4 o[8] = {};
    float m_run[4], l_run[4];
    #pragma unroll
    for (int r = 0; r < 4; ++r) { m_run[r] = -1e30f; l_run[r] = 0.0f; }

    char* Pb = Ps[w];
    uint4 vv[2];

    auto loadV = [&](int t) {
        const int kv0 = t * 64;
        #pragma unroll
        for (int it = 0; it < 2; ++it) {
            const int slot = it * 512 + tid;
            const int row = slot >> 4, c8 = slot & 15;
            vv[it] = *(const uint4*)(Vp + (size_t)(kv0 + row) * HD + c8 * 8);
        }
    };
    auto stageK = [&](int t, int buf) {
        const int kv0 = t * 64;
        #pragma unroll
        for (int it = 0; it < 2; ++it) {
            const int slot = it * 512 + tid;
            const int row = slot >> 4, c16 = slot & 15;
            const int srcb = c16 ^ (row & 7);   // pre-swizzled source, linear LDS dest
            async_copy16(Kp + (size_t)(kv0 + row) * HD + srcb * 8, Ks[buf] + slot * 16);
        }
    };
    auto writeV = [&](int buf) {
        #pragma unroll
        for (int it = 0; it < 2; ++it) {
            const int slot = it * 512 + tid;
            const int row = slot >> 4, c8 = slot & 15;
            const uint32_t wrd[4] = {vv[it].x, vv[it].y, vv[it].z, vv[it].w};
            #pragma unroll
            for (int p2 = 0; p2 < 4; ++p2) {
                const int d0 = c8 * 8 + p2 * 2, d1 = d0 + 1;
                int b0 = d0 * 128 + row * 2; b0 ^= (d0 & 7) << 4;
                int b1 = d1 * 128 + row * 2; b1 ^= (d1 & 7) << 4;
                *(ushort_t*)(Vt[buf] + b0) = (ushort_t)(wrd[p2] & 0xffffu);
                *(ushort_t*)(Vt[buf] + b1) = (ushort_t)(wrd[p2] >> 16);
            }
        }
    };

    // prologue: tile 0 in flight
    loadV(0);
    stageK(0, 0);

    int cur = 0;
    for (int t = 0; t < NT; ++t) {
        writeV(cur);                 // compiler waits vv here; K(t) drains at barrier
        __syncthreads();             // staging of tile t complete for all waves
        if (t + 1 < NT) {            // issue tile t+1 (in flight under compute)
            loadV(t + 1);
            stageK(t + 1, cur ^ 1);
        }

        const int kv0 = t * 64;
        const bool skipw = (kv0 > q0 + w * 16 + 15);   // wave-uniform: fully masked
        if (!skipw) {
            // S = Q K^T : col(lane&15)=kv, row((lane>>4)*4+r)=q
            f32x4 s[4] = {};
            #pragma unroll
            for (int ks = 0; ks < 4; ++ks) {
                #pragma unroll
                for (int nf = 0; nf < 4; ++nf) {
                    const int r   = nf * 16 + l15;
                    const int blk = (ks * 4 + lq) ^ (r & 7);
                    const f16x8 kf = *(const f16x8*)(Ks[cur] + r * 256 + blk * 16);
                    s[nf] = mfma16(qf[ks], kf, s[nf]);
                }
            }

            if (kv0 + 63 > q0 + w * 16) {   // diagonal-crossing for this wave
                #pragma unroll
                for (int nf = 0; nf < 4; ++nf) {
                    const int kvp = kv0 + nf * 16 + l15;
                    #pragma unroll
                    for (int r = 0; r < 4; ++r)
                        if (kvp > q0 + w * 16 + lq * 4 + r) s[nf][r] = -1e30f;
                }
            }

            // online softmax: row groups = 16 lanes sharing lq
            float alpha[4];
            #pragma unroll
            for (int r = 0; r < 4; ++r) {
                float v = fmaxf(fmaxf(s[0][r], s[1][r]), fmaxf(s[2][r], s[3][r]));
                v = fmaxf(v, __shfl_xor(v, 1));
                v = fmaxf(v, __shfl_xor(v, 2));
                v = fmaxf(v, __shfl_xor(v, 4));
                v = fmaxf(v, __shfl_xor(v, 8));
                const float mn = fmaxf(m_run[r], v);
                alpha[r] = __builtin_exp2f((m_run[r] - mn) * LOG2E);
                m_run[r] = mn;
            }

            float ps[4] = {0.f, 0.f, 0.f, 0.f};
            #pragma unroll
            for (int nf = 0; nf < 4; ++nf) {
                #pragma unroll
                for (int r = 0; r < 4; ++r) {
                    const float p = __builtin_exp2f((s[nf][r] - m_run[r]) * LOG2E);
                    ps[r] += p;
                    const int qp = lq * 4 + r;
                    int byt = qp * 128 + (nf * 16 + l15) * 2;
                    byt ^= (qp & 7) << 4;
                    union { _Float16 hf; ushort_t u; } cv;
                    cv.hf = (_Float16)p;
                    *(ushort_t*)(Pb + byt) = cv.u;  // wave-private, in-order LDS
                }
            }
            #pragma unroll
            for (int r = 0; r < 4; ++r) {
                float v = ps[r];
                v += __shfl_xor(v, 1);
                v += __shfl_xor(v, 2);
                v += __shfl_xor(v, 4);
                v += __shfl_xor(v, 8);
                l_run[r] = l_run[r] * alpha[r] + v;
            }
            #pragma unroll
            for (int df = 0; df < 8; ++df)
                #pragma unroll
                for (int r = 0; r < 4; ++r)
                    o[df][r] *= alpha[r];

            // O += P @ V
            #pragma unroll
            for (int ks2 = 0; ks2 < 2; ++ks2) {
                const int pblk = (ks2 * 4 + lq) ^ (l15 & 7);
                const f16x8 pf = *(const f16x8*)(Pb + l15 * 128 + pblk * 16);
                #pragma unroll
                for (int df = 0; df < 8; ++df) {
                    const int vr   = df * 16 + l15;
                    const int vblk = (ks2 * 4 + lq) ^ (vr & 7);
                    const f16x8 vf = *(const f16x8*)(Vt[cur] + vr * 128 + vblk * 16);
                    o[df] = mfma16(pf, vf, o[df]);
                }
            }
        }
        cur ^= 1;
    }

    #pragma unroll
    for (int r = 0; r < 4; ++r) l_run[r] = 1.0f / l_run[r];
    #pragma unroll
    for (int df = 0; df < 8; ++df) {
        #pragma unroll
        for (int r = 0; r < 4; ++r) {
            const int qg = q0 + w * 16 + lq * 4 + r;
            const int dg = df * 16 + l15;
            O[((size_t)(b * TSEQ + qg)) * HID + h * HD + dg] = (_Float16)(o[df][r] * l_run[r]);
        }
    }
}

extern "C" void kernel_launch(void* const* d_in, const int* in_sizes, int n_in,
                              void* d_out, int out_size, void* d_ws, size_t ws_size,
                              hipStream_t stream) {
    (void)in_sizes; (void)n_in; (void)out_size; (void)ws_size;
    const float* hs   = (const float*)d_in[0];
    const float* wqkv = (const float*)d_in[1];
    const float* wout = (const float*)d_in[2];

    // workspace layout (112 MiB total)
    char* ws = (char*)d_ws;
    size_t off = 0;
    _Float16* hs_h   = (_Float16*)(ws + off); off += (size_t)BATCH * TSEQ * HID * 2;
    _Float16* wqkv_h = (_Float16*)(ws + off); off += (size_t)3 * HID * HID * 2;
    _Float16* wout_h = (_Float16*)(ws + off); off += (size_t)HID * HID * 2;
    _Float16* Qh     = (_Float16*)(ws + off); off += (size_t)BATCH * NH * TSEQ * HD * 2;
    _Float16* Kh     = (_Float16*)(ws + off); off += (size_t)BATCH * NH * TSEQ * HD * 2;
    _Float16* Vh     = (_Float16*)(ws + off); off += (size_t)BATCH * NH * TSEQ * HD * 2;
    _Float16* At     = (_Float16*)(ws + off); off += (size_t)BATCH * TSEQ * HID * 2;

    const int n4_hs   = BATCH * TSEQ * HID / 4;
    const int n4_wqkv = 3 * HID * HID / 4;
    const int n4_wout = HID * HID / 4;
    cast_f32_f16<<<dim3((n4_hs   + 255) / 256), dim3(256), 0, stream>>>((const float4*)hs,   (f16x4*)hs_h,   n4_hs);
    cast_f32_f16<<<dim3((n4_wqkv + 255) / 256), dim3(256), 0, stream>>>((const float4*)wqkv, (f16x4*)wqkv_h, n4_wqkv);
    cast_f32_f16<<<dim3((n4_wout + 255) / 256), dim3(256), 0, stream>>>((const float4*)wout, (f16x4*)wout_h, n4_wout);

    gemm_bt<0><<<dim3(3 * HID / 128, BATCH * TSEQ / 128), dim3(256), 0, stream>>>(
        hs_h, wqkv_h, nullptr, Qh, Kh, Vh);

    attn_fwd<<<dim3(512), dim3(512), 0, stream>>>(Qh, Kh, Vh, At);

    gemm_bt<1><<<dim3(HID / 128, BATCH * TSEQ / 128), dim3(256), 0, stream>>>(
        At, wout_h, (float*)d_out, nullptr, nullptr, nullptr);
}

// Round 3
// 323.234 us; speedup vs baseline: 1.3052x; 1.1019x over previous
//
#include <hip/hip_runtime.h>
#include <cstdint>
#include <cstddef>

// ---- types ----
typedef _Float16 f16x8 __attribute__((ext_vector_type(8)));
typedef _Float16 f16x4 __attribute__((ext_vector_type(4)));
typedef float    f32x4 __attribute__((ext_vector_type(4)));
typedef unsigned short ushort_t;

#define LOG2E 1.4426950408889634f

constexpr int BATCH = 2;
constexpr int TSEQ  = 2048;
constexpr int HID   = 2048;
constexpr int NH    = 16;
constexpr int HD    = 128;
constexpr int GK    = 2048;   // K-dim of both GEMMs
constexpr int NKT   = GK / 64; // 32 K-tiles

__device__ inline f32x4 mfma16(f16x8 a, f16x8 b, f32x4 c) {
    return __builtin_amdgcn_mfma_f32_16x16x32_f16(a, b, c, 0, 0, 0);
}

// async global->LDS, 16B per lane; LDS dest must be linear (base + lane*16)
__device__ inline void async_copy16(const void* src, void* dst_lds) {
    __builtin_amdgcn_global_load_lds(
        (const __attribute__((address_space(1))) uint32_t*)src,
        (__attribute__((address_space(3))) uint32_t*)dst_lds, 16, 0, 0);
}

// ---- fp32 -> fp16 cast, vectorized (G13) ----
__global__ __launch_bounds__(256)
void cast_f32_f16(const float4* __restrict__ in, f16x4* __restrict__ out, int n4) {
    int i = blockIdx.x * 256 + threadIdx.x;
    if (i >= n4) return;
    float4 v = in[i];
    f16x4 o = { (_Float16)v.x, (_Float16)v.y, (_Float16)v.z, (_Float16)v.w };
    out[i] = o;
}

// ---- GEMM v2: C[M,N] = A[M,GK] @ B[N,GK]^T, pipelined 3-ring + counted vmcnt ----
// BM=256, BN=128, BK=64; 512 thr / 8 waves (4M x 2N); per-wave 64x64 out.
// T2 swizzle: pre-swizzled global source, linear LDS dest, XOR(row&7) read.
// T3/T4: stage 2 K-tiles ahead; s_waitcnt vmcnt(6) + RAW s_barrier (no drain).
// MODE 0: scatter to Q/K/V [B][NH][T][HD] fp16, Q scaled by 1/sqrt(HD)
// MODE 1: write fp32 C[M][HID] (= d_out)
template <int MODE>
__global__ __launch_bounds__(512, 2)
void gemm_bt(const _Float16* __restrict__ A, const _Float16* __restrict__ B,
             float* __restrict__ C, _Float16* __restrict__ Qo,
             _Float16* __restrict__ Ko, _Float16* __restrict__ Vo, int NB) {
    __shared__ __align__(16) _Float16 As[3][256 * 64];  // 32KB x3
    __shared__ __align__(16) _Float16 Bs[3][128 * 64];  // 16KB x3  (total 144KB)

    const int tid  = threadIdx.x;
    const int lane = tid & 63;
    const int w    = tid >> 6;        // wave 0..7
    const int l15  = lane & 15;
    const int lq   = lane >> 4;
    const int wr   = w >> 1, wc = w & 1;   // 4M x 2N wave grid

    // T1: XCD-aware block swizzle (gridDim.x % 8 == 0)
    const int bid = (int)blockIdx.x;
    const int cpx = (int)gridDim.x >> 3;
    const int swz = (bid & 7) * cpx + (bid >> 3);
    const int bn  = swz % NB, bm = swz / NB;
    const int m0  = bm * 256, n0 = bn * 128;

    const _Float16* Ab = A + (size_t)m0 * GK;
    const _Float16* Bb = B + (size_t)n0 * GK;

    auto stage = [&](int t, int b) {
        const int k0 = t * 64;
        #pragma unroll
        for (int it = 0; it < 4; ++it) {            // A: 256 rows x 8 chunks
            const int slot = it * 512 + tid;
            const int row = slot >> 3, c16 = slot & 7;
            const int srcb = c16 ^ (row & 7);       // inverse-swizzled source
            async_copy16(Ab + (size_t)row * GK + k0 + srcb * 8,
                         (char*)As[b] + slot * 16); // linear dest
        }
        #pragma unroll
        for (int it = 0; it < 2; ++it) {            // B: 128 rows x 8 chunks
            const int slot = it * 512 + tid;
            const int row = slot >> 3, c16 = slot & 7;
            const int srcb = c16 ^ (row & 7);
            async_copy16(Bb + (size_t)row * GK + k0 + srcb * 8,
                         (char*)Bs[b] + slot * 16);
        }
    };

    f32x4 acc[4][4] = {};

    stage(0, 0);
    stage(1, 1);

    for (int t = 0; t < NKT; ++t) {
        // my tile-t loads landed (all but newest 6 = tile t+1); then all waves'
        if (t + 1 < NKT) asm volatile("s_waitcnt vmcnt(6)" ::: "memory");
        else             asm volatile("s_waitcnt vmcnt(0)" ::: "memory");
        __builtin_amdgcn_s_barrier();
        __builtin_amdgcn_sched_barrier(0);

        const char* At_ = (const char*)As[t % 3];
        const char* Bt_ = (const char*)Bs[t % 3];

        f16x8 af[4][2], bff[4][2];
        #pragma unroll
        for (int i = 0; i < 4; ++i)
            #pragma unroll
            for (int kk = 0; kk < 2; ++kk) {
                const int ra = wr * 64 + i * 16 + l15;
                af[i][kk]  = *(const f16x8*)(At_ + ra * 128 + (((kk * 4 + lq) ^ (ra & 7)) << 4));
                const int rb = wc * 64 + i * 16 + l15;
                bff[i][kk] = *(const f16x8*)(Bt_ + rb * 128 + (((kk * 4 + lq) ^ (rb & 7)) << 4));
            }

        if (t + 2 < NKT) stage(t + 2, (t + 2) % 3);   // overwrites buf of tile t-1

        __builtin_amdgcn_s_setprio(1);
        #pragma unroll
        for (int kk = 0; kk < 2; ++kk)
            #pragma unroll
            for (int i = 0; i < 4; ++i)
                #pragma unroll
                for (int j = 0; j < 4; ++j)
                    acc[i][j] = mfma16(af[i][kk], bff[j][kk], acc[i][j]);
        __builtin_amdgcn_s_setprio(0);
    }

    if (MODE == 0) {
        #pragma unroll
        for (int j = 0; j < 4; ++j) {
            const int ncol = n0 + wc * 64 + j * 16 + l15;
            const int which = ncol >> 11;          // 0=Q 1=K 2=V
            const int oo = ncol & 2047;
            const int head = oo >> 7;
            const int d = oo & 127;
            _Float16* dst = (which == 0) ? Qo : (which == 1) ? Ko : Vo;
            const float scl = (which == 0) ? 0.08838834764831845f : 1.0f;
            #pragma unroll
            for (int i = 0; i < 4; ++i) {
                #pragma unroll
                for (int r = 0; r < 4; ++r) {
                    const int m = m0 + wr * 64 + i * 16 + lq * 4 + r;
                    const int b = m >> 11, tt = m & 2047;
                    dst[((size_t)(b * NH + head) * TSEQ + tt) * HD + d] =
                        (_Float16)(acc[i][j][r] * scl);
                }
            }
        }
    } else {
        #pragma unroll
        for (int i = 0; i < 4; ++i)
            #pragma unroll
            for (int j = 0; j < 4; ++j)
                #pragma unroll
                for (int r = 0; r < 4; ++r) {
                    const int m = m0 + wr * 64 + i * 16 + lq * 4 + r;
                    const int n = n0 + wc * 64 + j * 16 + l15;
                    C[(size_t)m * HID + n] = acc[i][j][r];
                }
    }
}

// ---- causal flash attention (unchanged from R1: 8 waves, QBLK=128, dbuf, 1 barrier/tile) ----
__global__ __launch_bounds__(512)
void attn_fwd(const _Float16* __restrict__ Q, const _Float16* __restrict__ K,
              const _Float16* __restrict__ V, _Float16* __restrict__ O) {
    __shared__ __align__(16) char Ks[2][64 * 256];
    __shared__ __align__(16) char Vt[2][128 * 128];
    __shared__ __align__(16) char Ps[8][2048];

    const int tid  = threadIdx.x;
    const int lane = tid & 63;
    const int w    = tid >> 6;
    const int l15  = lane & 15;
    const int lq   = lane >> 4;

    const int qt = 15 - ((int)blockIdx.x >> 5);
    const int bh = (int)blockIdx.x & 31;
    const int b = bh >> 4, h = bh & 15;

    const size_t base = (size_t)bh * TSEQ * HD;
    const _Float16* Qp = Q + base;
    const _Float16* Kp = K + base;
    const _Float16* Vp = V + base;

    const int q0 = qt * 128;
    const int NT = 2 * qt + 2;

    const int qrow = q0 + w * 16 + l15;
    f16x8 qf[4];
    #pragma unroll
    for (int ks = 0; ks < 4; ++ks)
        qf[ks] = *(const f16x8*)(Qp + (size_t)qrow * HD + ks * 32 + lq * 8);

    f32x4 o[8] = {};
    float m_run[4], l_run[4];
    #pragma unroll
    for (int r = 0; r < 4; ++r) { m_run[r] = -1e30f; l_run[r] = 0.0f; }

    char* Pb = Ps[w];
    uint4 vv[2];

    auto loadV = [&](int t) {
        const int kv0 = t * 64;
        #pragma unroll
        for (int it = 0; it < 2; ++it) {
            const int slot = it * 512 + tid;
            const int row = slot >> 4, c8 = slot & 15;
            vv[it] = *(const uint4*)(Vp + (size_t)(kv0 + row) * HD + c8 * 8);
        }
    };
    auto stageK = [&](int t, int buf) {
        const int kv0 = t * 64;
        #pragma unroll
        for (int it = 0; it < 2; ++it) {
            const int slot = it * 512 + tid;
            const int row = slot >> 4, c16 = slot & 15;
            const int srcb = c16 ^ (row & 7);
            async_copy16(Kp + (size_t)(kv0 + row) * HD + srcb * 8, Ks[buf] + slot * 16);
        }
    };
    auto writeV = [&](int buf) {
        #pragma unroll
        for (int it = 0; it < 2; ++it) {
            const int slot = it * 512 + tid;
            const int row = slot >> 4, c8 = slot & 15;
            const uint32_t wrd[4] = {vv[it].x, vv[it].y, vv[it].z, vv[it].w};
            #pragma unroll
            for (int p2 = 0; p2 < 4; ++p2) {
                const int d0 = c8 * 8 + p2 * 2, d1 = d0 + 1;
                int b0 = d0 * 128 + row * 2; b0 ^= (d0 & 7) << 4;
                int b1 = d1 * 128 + row * 2; b1 ^= (d1 & 7) << 4;
                *(ushort_t*)(Vt[buf] + b0) = (ushort_t)(wrd[p2] & 0xffffu);
                *(ushort_t*)(Vt[buf] + b1) = (ushort_t)(wrd[p2] >> 16);
            }
        }
    };

    loadV(0);
    stageK(0, 0);

    int cur = 0;
    for (int t = 0; t < NT; ++t) {
        writeV(cur);
        __syncthreads();
        if (t + 1 < NT) {
            loadV(t + 1);
            stageK(t + 1, cur ^ 1);
        }

        const int kv0 = t * 64;
        const bool skipw = (kv0 > q0 + w * 16 + 15);
        if (!skipw) {
            f32x4 s[4] = {};
            #pragma unroll
            for (int ks = 0; ks < 4; ++ks) {
                #pragma unroll
                for (int nf = 0; nf < 4; ++nf) {
                    const int r   = nf * 16 + l15;
                    const int blk = (ks * 4 + lq) ^ (r & 7);
                    const f16x8 kf = *(const f16x8*)(Ks[cur] + r * 256 + blk * 16);
                    s[nf] = mfma16(qf[ks], kf, s[nf]);
                }
            }

            if (kv0 + 63 > q0 + w * 16) {
                #pragma unroll
                for (int nf = 0; nf < 4; ++nf) {
                    const int kvp = kv0 + nf * 16 + l15;
                    #pragma unroll
                    for (int r = 0; r < 4; ++r)
                        if (kvp > q0 + w * 16 + lq * 4 + r) s[nf][r] = -1e30f;
                }
            }

            float alpha[4];
            #pragma unroll
            for (int r = 0; r < 4; ++r) {
                float v = fmaxf(fmaxf(s[0][r], s[1][r]), fmaxf(s[2][r], s[3][r]));
                v = fmaxf(v, __shfl_xor(v, 1));
                v = fmaxf(v, __shfl_xor(v, 2));
                v = fmaxf(v, __shfl_xor(v, 4));
                v = fmaxf(v, __shfl_xor(v, 8));
                const float mn = fmaxf(m_run[r], v);
                alpha[r] = __builtin_exp2f((m_run[r] - mn) * LOG2E);
                m_run[r] = mn;
            }

            float ps[4] = {0.f, 0.f, 0.f, 0.f};
            #pragma unroll
            for (int nf = 0; nf < 4; ++nf) {
                #pragma unroll
                for (int r = 0; r < 4; ++r) {
                    const float p = __builtin_exp2f((s[nf][r] - m_run[r]) * LOG2E);
                    ps[r] += p;
                    const int qp = lq * 4 + r;
                    int byt = qp * 128 + (nf * 16 + l15) * 2;
                    byt ^= (qp & 7) << 4;
                    union { _Float16 hf; ushort_t u; } cv;
                    cv.hf = (_Float16)p;
                    *(ushort_t*)(Pb + byt) = cv.u;
                }
            }
            #pragma unroll
            for (int r = 0; r < 4; ++r) {
                float v = ps[r];
                v += __shfl_xor(v, 1);
                v += __shfl_xor(v, 2);
                v += __shfl_xor(v, 4);
                v += __shfl_xor(v, 8);
                l_run[r] = l_run[r] * alpha[r] + v;
            }
            #pragma unroll
            for (int df = 0; df < 8; ++df)
                #pragma unroll
                for (int r = 0; r < 4; ++r)
                    o[df][r] *= alpha[r];

            #pragma unroll
            for (int ks2 = 0; ks2 < 2; ++ks2) {
                const int pblk = (ks2 * 4 + lq) ^ (l15 & 7);
                const f16x8 pf = *(const f16x8*)(Pb + l15 * 128 + pblk * 16);
                #pragma unroll
                for (int df = 0; df < 8; ++df) {
                    const int vr   = df * 16 + l15;
                    const int vblk = (ks2 * 4 + lq) ^ (vr & 7);
                    const f16x8 vf = *(const f16x8*)(Vt[cur] + vr * 128 + vblk * 16);
                    o[df] = mfma16(pf, vf, o[df]);
                }
            }
        }
        cur ^= 1;
    }

    #pragma unroll
    for (int r = 0; r < 4; ++r) l_run[r] = 1.0f / l_run[r];
    #pragma unroll
    for (int df = 0; df < 8; ++df) {
        #pragma unroll
        for (int r = 0; r < 4; ++r) {
            const int qg = q0 + w * 16 + lq * 4 + r;
            const int dg = df * 16 + l15;
            O[((size_t)(b * TSEQ + qg)) * HID + h * HD + dg] = (_Float16)(o[df][r] * l_run[r]);
        }
    }
}

extern "C" void kernel_launch(void* const* d_in, const int* in_sizes, int n_in,
                              void* d_out, int out_size, void* d_ws, size_t ws_size,
                              hipStream_t stream) {
    (void)in_sizes; (void)n_in; (void)out_size; (void)ws_size;
    const float* hs   = (const float*)d_in[0];
    const float* wqkv = (const float*)d_in[1];
    const float* wout = (const float*)d_in[2];

    char* ws = (char*)d_ws;
    size_t off = 0;
    _Float16* hs_h   = (_Float16*)(ws + off); off += (size_t)BATCH * TSEQ * HID * 2;
    _Float16* wqkv_h = (_Float16*)(ws + off); off += (size_t)3 * HID * HID * 2;
    _Float16* wout_h = (_Float16*)(ws + off); off += (size_t)HID * HID * 2;
    _Float16* Qh     = (_Float16*)(ws + off); off += (size_t)BATCH * NH * TSEQ * HD * 2;
    _Float16* Kh     = (_Float16*)(ws + off); off += (size_t)BATCH * NH * TSEQ * HD * 2;
    _Float16* Vh     = (_Float16*)(ws + off); off += (size_t)BATCH * NH * TSEQ * HD * 2;
    _Float16* At     = (_Float16*)(ws + off); off += (size_t)BATCH * TSEQ * HID * 2;

    const int n4_hs   = BATCH * TSEQ * HID / 4;
    const int n4_wqkv = 3 * HID * HID / 4;
    const int n4_wout = HID * HID / 4;
    cast_f32_f16<<<dim3((n4_hs   + 255) / 256), dim3(256), 0, stream>>>((const float4*)hs,   (f16x4*)hs_h,   n4_hs);
    cast_f32_f16<<<dim3((n4_wqkv + 255) / 256), dim3(256), 0, stream>>>((const float4*)wqkv, (f16x4*)wqkv_h, n4_wqkv);
    cast_f32_f16<<<dim3((n4_wout + 255) / 256), dim3(256), 0, stream>>>((const float4*)wout, (f16x4*)wout_h, n4_wout);

    // GEMM1: M=4096 (B*T), N=6144 (3H): grid 16x48 = 768 blocks
    gemm_bt<0><<<dim3(768), dim3(512), 0, stream>>>(
        hs_h, wqkv_h, nullptr, Qh, Kh, Vh, 48);

    attn_fwd<<<dim3(512), dim3(512), 0, stream>>>(Qh, Kh, Vh, At);

    // GEMM2: M=4096, N=2048: grid 16x16 = 256 blocks
    gemm_bt<1><<<dim3(256), dim3(512), 0, stream>>>(
        At, wout_h, (float*)d_out, nullptr, nullptr, nullptr, 16);
}

// Round 4
// 294.089 us; speedup vs baseline: 1.4345x; 1.0991x over previous
//
#include <hip/hip_runtime.h>
#include <cstdint>
#include <cstddef>

// ---- types ----
typedef _Float16 f16x8 __attribute__((ext_vector_type(8)));
typedef _Float16 f16x4 __attribute__((ext_vector_type(4)));
typedef float    f32x4 __attribute__((ext_vector_type(4)));
typedef unsigned short ushort_t;

#define LOG2E 1.4426950408889634f

constexpr int BATCH = 2;
constexpr int TSEQ  = 2048;
constexpr int HID   = 2048;
constexpr int NH    = 16;
constexpr int HD    = 128;
constexpr int GK    = 2048;   // K-dim of both GEMMs
constexpr int NKT   = GK / 64; // 32 K-tiles

__device__ inline f32x4 mfma16(f16x8 a, f16x8 b, f32x4 c) {
    return __builtin_amdgcn_mfma_f32_16x16x32_f16(a, b, c, 0, 0, 0);
}

// async global->LDS, 16B per lane; LDS dest must be linear (base + lane*16)
__device__ inline void async_copy16(const void* src, void* dst_lds) {
    __builtin_amdgcn_global_load_lds(
        (const __attribute__((address_space(1))) uint32_t*)src,
        (__attribute__((address_space(3))) uint32_t*)dst_lds, 16, 0, 0);
}

// ---- fp32 -> fp16 cast, vectorized (G13) ----
__global__ __launch_bounds__(256)
void cast_f32_f16(const float4* __restrict__ in, f16x4* __restrict__ out, int n4) {
    int i = blockIdx.x * 256 + threadIdx.x;
    if (i >= n4) return;
    float4 v = in[i];
    f16x4 o = { (_Float16)v.x, (_Float16)v.y, (_Float16)v.z, (_Float16)v.w };
    out[i] = o;
}

// ---- GEMM v2 (unchanged from R3): 3-ring pipeline, counted vmcnt, T2 swizzle ----
template <int MODE>
__global__ __launch_bounds__(512, 2)
void gemm_bt(const _Float16* __restrict__ A, const _Float16* __restrict__ B,
             float* __restrict__ C, _Float16* __restrict__ Qo,
             _Float16* __restrict__ Ko, _Float16* __restrict__ Vo, int NB) {
    __shared__ __align__(16) _Float16 As[3][256 * 64];
    __shared__ __align__(16) _Float16 Bs[3][128 * 64];

    const int tid  = threadIdx.x;
    const int lane = tid & 63;
    const int w    = tid >> 6;
    const int l15  = lane & 15;
    const int lq   = lane >> 4;
    const int wr   = w >> 1, wc = w & 1;

    const int bid = (int)blockIdx.x;
    const int cpx = (int)gridDim.x >> 3;
    const int swz = (bid & 7) * cpx + (bid >> 3);
    const int bn  = swz % NB, bm = swz / NB;
    const int m0  = bm * 256, n0 = bn * 128;

    const _Float16* Ab = A + (size_t)m0 * GK;
    const _Float16* Bb = B + (size_t)n0 * GK;

    auto stage = [&](int t, int b) {
        const int k0 = t * 64;
        #pragma unroll
        for (int it = 0; it < 4; ++it) {
            const int slot = it * 512 + tid;
            const int row = slot >> 3, c16 = slot & 7;
            const int srcb = c16 ^ (row & 7);
            async_copy16(Ab + (size_t)row * GK + k0 + srcb * 8,
                         (char*)As[b] + slot * 16);
        }
        #pragma unroll
        for (int it = 0; it < 2; ++it) {
            const int slot = it * 512 + tid;
            const int row = slot >> 3, c16 = slot & 7;
            const int srcb = c16 ^ (row & 7);
            async_copy16(Bb + (size_t)row * GK + k0 + srcb * 8,
                         (char*)Bs[b] + slot * 16);
        }
    };

    f32x4 acc[4][4] = {};

    stage(0, 0);
    stage(1, 1);

    for (int t = 0; t < NKT; ++t) {
        if (t + 1 < NKT) asm volatile("s_waitcnt vmcnt(6)" ::: "memory");
        else             asm volatile("s_waitcnt vmcnt(0)" ::: "memory");
        __builtin_amdgcn_s_barrier();
        __builtin_amdgcn_sched_barrier(0);

        const char* At_ = (const char*)As[t % 3];
        const char* Bt_ = (const char*)Bs[t % 3];

        f16x8 af[4][2], bff[4][2];
        #pragma unroll
        for (int i = 0; i < 4; ++i)
            #pragma unroll
            for (int kk = 0; kk < 2; ++kk) {
                const int ra = wr * 64 + i * 16 + l15;
                af[i][kk]  = *(const f16x8*)(At_ + ra * 128 + (((kk * 4 + lq) ^ (ra & 7)) << 4));
                const int rb = wc * 64 + i * 16 + l15;
                bff[i][kk] = *(const f16x8*)(Bt_ + rb * 128 + (((kk * 4 + lq) ^ (rb & 7)) << 4));
            }

        if (t + 2 < NKT) stage(t + 2, (t + 2) % 3);

        __builtin_amdgcn_s_setprio(1);
        #pragma unroll
        for (int kk = 0; kk < 2; ++kk)
            #pragma unroll
            for (int i = 0; i < 4; ++i)
                #pragma unroll
                for (int j = 0; j < 4; ++j)
                    acc[i][j] = mfma16(af[i][kk], bff[j][kk], acc[i][j]);
        __builtin_amdgcn_s_setprio(0);
    }

    if (MODE == 0) {
        #pragma unroll
        for (int j = 0; j < 4; ++j) {
            const int ncol = n0 + wc * 64 + j * 16 + l15;
            const int which = ncol >> 11;
            const int oo = ncol & 2047;
            const int head = oo >> 7;
            const int d = oo & 127;
            _Float16* dst = (which == 0) ? Qo : (which == 1) ? Ko : Vo;
            const float scl = (which == 0) ? 0.08838834764831845f : 1.0f;
            #pragma unroll
            for (int i = 0; i < 4; ++i) {
                #pragma unroll
                for (int r = 0; r < 4; ++r) {
                    const int m = m0 + wr * 64 + i * 16 + lq * 4 + r;
                    const int b = m >> 11, tt = m & 2047;
                    dst[((size_t)(b * NH + head) * TSEQ + tt) * HD + d] =
                        (_Float16)(acc[i][j][r] * scl);
                }
            }
        }
    } else {
        #pragma unroll
        for (int i = 0; i < 4; ++i)
            #pragma unroll
            for (int j = 0; j < 4; ++j)
                #pragma unroll
                for (int r = 0; r < 4; ++r) {
                    const int m = m0 + wr * 64 + i * 16 + lq * 4 + r;
                    const int n = n0 + wc * 64 + j * 16 + l15;
                    C[(size_t)m * HID + n] = acc[i][j][r];
                }
    }
}

// ---- causal flash attention v3 ----
// 256 blocks; each handles paired q-tiles (15-pair, pair) -> uniform 34 kv-tiles.
// Conflict-free writeV (lane=kv row, 2-way free). Defer-max (T13). setprio (T5).
__global__ __launch_bounds__(512)
void attn_fwd(const _Float16* __restrict__ Q, const _Float16* __restrict__ K,
              const _Float16* __restrict__ V, _Float16* __restrict__ O) {
    __shared__ __align__(16) char Ks[2][64 * 256];   // [64][128] f16, swizzled
    __shared__ __align__(16) char Vt[2][128 * 128];  // [128][64] f16 (V^T), swizzled
    __shared__ __align__(16) char Ps[8][2048];       // per-wave [16][64] f16 P

    const int tid  = threadIdx.x;
    const int lane = tid & 63;
    const int w    = tid >> 6;      // 0..7
    const int l15  = lane & 15;
    const int lq   = lane >> 4;

    const int bh   = (int)blockIdx.x & 31;   // same-bh blocks land on same XCD (%8 rr)
    const int pair = (int)blockIdx.x >> 5;   // 0..7
    const int b = bh >> 4, h = bh & 15;

    const size_t base = (size_t)bh * TSEQ * HD;
    const _Float16* Qp = Q + base;
    const _Float16* Kp = K + base;
    const _Float16* Vp = V + base;

    uint4 vv[2];
    auto loadV = [&](int t) {   // lane = kv row; wave w owns d-chunks {w, w+8}
        #pragma unroll
        for (int it = 0; it < 2; ++it) {
            const int c8 = it * 8 + w;
            vv[it] = *(const uint4*)(Vp + (size_t)(t * 64 + lane) * HD + c8 * 8);
        }
    };
    auto stageK = [&](int t, int buf) {
        #pragma unroll
        for (int it = 0; it < 2; ++it) {
            const int slot = it * 512 + tid;
            const int row = slot >> 4, c16 = slot & 15;
            const int srcb = c16 ^ (row & 7);
            async_copy16(Kp + (size_t)(t * 64 + row) * HD + srcb * 8, Ks[buf] + slot * 16);
        }
    };
    auto writeV = [&](int buf) {   // ushort stores at d*128 + lane*2: 32 banks, 2-way free
        #pragma unroll
        for (int it = 0; it < 2; ++it) {
            const int c8 = it * 8 + w;
            const uint32_t wrd[4] = {vv[it].x, vv[it].y, vv[it].z, vv[it].w};
            #pragma unroll
            for (int p2 = 0; p2 < 4; ++p2) {
                const int d0 = c8 * 8 + p2 * 2, d1 = d0 + 1;
                int b0 = d0 * 128 + lane * 2; b0 ^= (d0 & 7) << 4;
                int b1 = d1 * 128 + lane * 2; b1 ^= (d1 & 7) << 4;
                *(ushort_t*)(Vt[buf] + b0) = (ushort_t)(wrd[p2] & 0xffffu);
                *(ushort_t*)(Vt[buf] + b1) = (ushort_t)(wrd[p2] >> 16);
            }
        }
    };

    char* Pb = Ps[w];

    for (int phase = 0; phase < 2; ++phase) {
        const int qt = phase ? pair : (15 - pair);
        const int q0 = qt * 128;
        const int NT = 2 * qt + 2;

        if (phase) __syncthreads();   // LDS reuse guard across phases

        const int qrow = q0 + w * 16 + l15;
        f16x8 qf[4];
        #pragma unroll
        for (int ks = 0; ks < 4; ++ks)
            qf[ks] = *(const f16x8*)(Qp + (size_t)qrow * HD + ks * 32 + lq * 8);

        f32x4 o[8] = {};
        float m_run[4], l_run[4];
        #pragma unroll
        for (int r = 0; r < 4; ++r) { m_run[r] = -1e30f; l_run[r] = 0.0f; }

        loadV(0);
        stageK(0, 0);

        int cur = 0;
        for (int t = 0; t < NT; ++t) {
            writeV(cur);
            __syncthreads();
            if (t + 1 < NT) {
                loadV(t + 1);
                stageK(t + 1, cur ^ 1);
            }

            const int kv0 = t * 64;
            // S = Q K^T
            f32x4 s[4] = {};
            __builtin_amdgcn_s_setprio(1);
            #pragma unroll
            for (int ks = 0; ks < 4; ++ks) {
                #pragma unroll
                for (int nf = 0; nf < 4; ++nf) {
                    const int r   = nf * 16 + l15;
                    const int blk = (ks * 4 + lq) ^ (r & 7);
                    const f16x8 kf = *(const f16x8*)(Ks[cur] + r * 256 + blk * 16);
                    s[nf] = mfma16(qf[ks], kf, s[nf]);
                }
            }
            __builtin_amdgcn_s_setprio(0);

            if (kv0 + 63 > q0 + w * 16) {   // diagonal-crossing for this wave
                #pragma unroll
                for (int nf = 0; nf < 4; ++nf) {
                    const int kvp = kv0 + nf * 16 + l15;
                    #pragma unroll
                    for (int r = 0; r < 4; ++r)
                        if (kvp > q0 + w * 16 + lq * 4 + r) s[nf][r] = -1e30f;
                }
            }

            // tile max per row-group
            float tmax[4];
            bool need = false;
            #pragma unroll
            for (int r = 0; r < 4; ++r) {
                float v = fmaxf(fmaxf(s[0][r], s[1][r]), fmaxf(s[2][r], s[3][r]));
                v = fmaxf(v, __shfl_xor(v, 1));
                v = fmaxf(v, __shfl_xor(v, 2));
                v = fmaxf(v, __shfl_xor(v, 4));
                v = fmaxf(v, __shfl_xor(v, 8));
                tmax[r] = v;
                need = need || (v > m_run[r] + 5.0f);   // T13 defer-max, THR=5
            }
            if (__any(need)) {
                float alpha[4];
                #pragma unroll
                for (int r = 0; r < 4; ++r) {
                    const float mn = fmaxf(m_run[r], tmax[r]);
                    alpha[r] = __builtin_exp2f((m_run[r] - mn) * LOG2E);
                    m_run[r] = mn;
                    l_run[r] *= alpha[r];
                }
                #pragma unroll
                for (int df = 0; df < 8; ++df)
                    #pragma unroll
                    for (int r = 0; r < 4; ++r)
                        o[df][r] *= alpha[r];
            }

            float ps[4] = {0.f, 0.f, 0.f, 0.f};
            #pragma unroll
            for (int nf = 0; nf < 4; ++nf) {
                #pragma unroll
                for (int r = 0; r < 4; ++r) {
                    const float p = __builtin_exp2f((s[nf][r] - m_run[r]) * LOG2E);
                    ps[r] += p;
                    const int qp = lq * 4 + r;
                    int byt = qp * 128 + (nf * 16 + l15) * 2;
                    byt ^= (qp & 7) << 4;
                    union { _Float16 hf; ushort_t u; } cv;
                    cv.hf = (_Float16)p;
                    *(ushort_t*)(Pb + byt) = cv.u;   // wave-private, in-order LDS
                }
            }
            #pragma unroll
            for (int r = 0; r < 4; ++r) {
                float v = ps[r];
                v += __shfl_xor(v, 1);
                v += __shfl_xor(v, 2);
                v += __shfl_xor(v, 4);
                v += __shfl_xor(v, 8);
                l_run[r] += v;
            }

            // O += P @ V
            __builtin_amdgcn_s_setprio(1);
            #pragma unroll
            for (int ks2 = 0; ks2 < 2; ++ks2) {
                const int pblk = (ks2 * 4 + lq) ^ (l15 & 7);
                const f16x8 pf = *(const f16x8*)(Pb + l15 * 128 + pblk * 16);
                #pragma unroll
                for (int df = 0; df < 8; ++df) {
                    const int vr   = df * 16 + l15;
                    const int vblk = (ks2 * 4 + lq) ^ (vr & 7);
                    const f16x8 vf = *(const f16x8*)(Vt[cur] + vr * 128 + vblk * 16);
                    o[df] = mfma16(pf, vf, o[df]);
                }
            }
            __builtin_amdgcn_s_setprio(0);
            cur ^= 1;
        }

        #pragma unroll
        for (int r = 0; r < 4; ++r) l_run[r] = 1.0f / l_run[r];
        #pragma unroll
        for (int df = 0; df < 8; ++df) {
            #pragma unroll
            for (int r = 0; r < 4; ++r) {
                const int qg = q0 + w * 16 + lq * 4 + r;
                const int dg = df * 16 + l15;
                O[((size_t)(b * TSEQ + qg)) * HID + h * HD + dg] =
                    (_Float16)(o[df][r] * l_run[r]);
            }
        }
    }
}

extern "C" void kernel_launch(void* const* d_in, const int* in_sizes, int n_in,
                              void* d_out, int out_size, void* d_ws, size_t ws_size,
                              hipStream_t stream) {
    (void)in_sizes; (void)n_in; (void)out_size; (void)ws_size;
    const float* hs   = (const float*)d_in[0];
    const float* wqkv = (const float*)d_in[1];
    const float* wout = (const float*)d_in[2];

    char* ws = (char*)d_ws;
    size_t off = 0;
    _Float16* hs_h   = (_Float16*)(ws + off); off += (size_t)BATCH * TSEQ * HID * 2;
    _Float16* wqkv_h = (_Float16*)(ws + off); off += (size_t)3 * HID * HID * 2;
    _Float16* wout_h = (_Float16*)(ws + off); off += (size_t)HID * HID * 2;
    _Float16* Qh     = (_Float16*)(ws + off); off += (size_t)BATCH * NH * TSEQ * HD * 2;
    _Float16* Kh     = (_Float16*)(ws + off); off += (size_t)BATCH * NH * TSEQ * HD * 2;
    _Float16* Vh     = (_Float16*)(ws + off); off += (size_t)BATCH * NH * TSEQ * HD * 2;
    _Float16* At     = (_Float16*)(ws + off); off += (size_t)BATCH * TSEQ * HID * 2;

    const int n4_hs   = BATCH * TSEQ * HID / 4;
    const int n4_wqkv = 3 * HID * HID / 4;
    const int n4_wout = HID * HID / 4;
    cast_f32_f16<<<dim3((n4_hs   + 255) / 256), dim3(256), 0, stream>>>((const float4*)hs,   (f16x4*)hs_h,   n4_hs);
    cast_f32_f16<<<dim3((n4_wqkv + 255) / 256), dim3(256), 0, stream>>>((const float4*)wqkv, (f16x4*)wqkv_h, n4_wqkv);
    cast_f32_f16<<<dim3((n4_wout + 255) / 256), dim3(256), 0, stream>>>((const float4*)wout, (f16x4*)wout_h, n4_wout);

    gemm_bt<0><<<dim3(768), dim3(512), 0, stream>>>(
        hs_h, wqkv_h, nullptr, Qh, Kh, Vh, 48);

    attn_fwd<<<dim3(256), dim3(512), 0, stream>>>(Qh, Kh, Vh, At);

    gemm_bt<1><<<dim3(256), dim3(512), 0, stream>>>(
        At, wout_h, (float*)d_out, nullptr, nullptr, nullptr, 16);
}

// Round 5
// 274.071 us; speedup vs baseline: 1.5393x; 1.0730x over previous
//
#include <hip/hip_runtime.h>
#include <cstdint>
#include <cstddef>

// ---- types ----
typedef _Float16 f16x8 __attribute__((ext_vector_type(8)));
typedef _Float16 f16x4 __attribute__((ext_vector_type(4)));
typedef float    f32x4 __attribute__((ext_vector_type(4)));
typedef unsigned short ushort_t;

#define LOG2E 1.4426950408889634f

constexpr int BATCH = 2;
constexpr int TSEQ  = 2048;
constexpr int HID   = 2048;
constexpr int NH    = 16;
constexpr int HD    = 128;
constexpr int GK    = 2048;   // K-dim of both GEMMs
constexpr int NKT   = GK / 64; // 32 K-tiles

__device__ inline f32x4 mfma16(f16x8 a, f16x8 b, f32x4 c) {
    return __builtin_amdgcn_mfma_f32_16x16x32_f16(a, b, c, 0, 0, 0);
}

// async global->LDS, 16B per lane; LDS dest must be linear (base + lane*16)
__device__ inline void async_copy16(const void* src, void* dst_lds) {
    __builtin_amdgcn_global_load_lds(
        (const __attribute__((address_space(1))) uint32_t*)src,
        (__attribute__((address_space(3))) uint32_t*)dst_lds, 16, 0, 0);
}

// ---- fp32 -> fp16 cast, vectorized (G13) ----
__global__ __launch_bounds__(256)
void cast_f32_f16(const float4* __restrict__ in, f16x4* __restrict__ out, int n4) {
    int i = blockIdx.x * 256 + threadIdx.x;
    if (i >= n4) return;
    float4 v = in[i];
    f16x4 o = { (_Float16)v.x, (_Float16)v.y, (_Float16)v.z, (_Float16)v.w };
    out[i] = o;
}

// ---- GEMM v2 (unchanged): 3-ring pipeline, counted vmcnt, T2 swizzle ----
template <int MODE>
__global__ __launch_bounds__(512, 2)
void gemm_bt(const _Float16* __restrict__ A, const _Float16* __restrict__ B,
             float* __restrict__ C, _Float16* __restrict__ Qo,
             _Float16* __restrict__ Ko, _Float16* __restrict__ Vo, int NB) {
    __shared__ __align__(16) _Float16 As[3][256 * 64];
    __shared__ __align__(16) _Float16 Bs[3][128 * 64];

    const int tid  = threadIdx.x;
    const int lane = tid & 63;
    const int w    = tid >> 6;
    const int l15  = lane & 15;
    const int lq   = lane >> 4;
    const int wr   = w >> 1, wc = w & 1;

    const int bid = (int)blockIdx.x;
    const int cpx = (int)gridDim.x >> 3;
    const int swz = (bid & 7) * cpx + (bid >> 3);
    const int bn  = swz % NB, bm = swz / NB;
    const int m0  = bm * 256, n0 = bn * 128;

    const _Float16* Ab = A + (size_t)m0 * GK;
    const _Float16* Bb = B + (size_t)n0 * GK;

    auto stage = [&](int t, int b) {
        const int k0 = t * 64;
        #pragma unroll
        for (int it = 0; it < 4; ++it) {
            const int slot = it * 512 + tid;
            const int row = slot >> 3, c16 = slot & 7;
            const int srcb = c16 ^ (row & 7);
            async_copy16(Ab + (size_t)row * GK + k0 + srcb * 8,
                         (char*)As[b] + slot * 16);
        }
        #pragma unroll
        for (int it = 0; it < 2; ++it) {
            const int slot = it * 512 + tid;
            const int row = slot >> 3, c16 = slot & 7;
            const int srcb = c16 ^ (row & 7);
            async_copy16(Bb + (size_t)row * GK + k0 + srcb * 8,
                         (char*)Bs[b] + slot * 16);
        }
    };

    f32x4 acc[4][4] = {};

    stage(0, 0);
    stage(1, 1);

    for (int t = 0; t < NKT; ++t) {
        if (t + 1 < NKT) asm volatile("s_waitcnt vmcnt(6)" ::: "memory");
        else             asm volatile("s_waitcnt vmcnt(0)" ::: "memory");
        __builtin_amdgcn_s_barrier();
        __builtin_amdgcn_sched_barrier(0);

        const char* At_ = (const char*)As[t % 3];
        const char* Bt_ = (const char*)Bs[t % 3];

        f16x8 af[4][2], bff[4][2];
        #pragma unroll
        for (int i = 0; i < 4; ++i)
            #pragma unroll
            for (int kk = 0; kk < 2; ++kk) {
                const int ra = wr * 64 + i * 16 + l15;
                af[i][kk]  = *(const f16x8*)(At_ + ra * 128 + (((kk * 4 + lq) ^ (ra & 7)) << 4));
                const int rb = wc * 64 + i * 16 + l15;
                bff[i][kk] = *(const f16x8*)(Bt_ + rb * 128 + (((kk * 4 + lq) ^ (rb & 7)) << 4));
            }

        if (t + 2 < NKT) stage(t + 2, (t + 2) % 3);

        __builtin_amdgcn_s_setprio(1);
        #pragma unroll
        for (int kk = 0; kk < 2; ++kk)
            #pragma unroll
            for (int i = 0; i < 4; ++i)
                #pragma unroll
                for (int j = 0; j < 4; ++j)
                    acc[i][j] = mfma16(af[i][kk], bff[j][kk], acc[i][j]);
        __builtin_amdgcn_s_setprio(0);
    }

    if (MODE == 0) {
        #pragma unroll
        for (int j = 0; j < 4; ++j) {
            const int ncol = n0 + wc * 64 + j * 16 + l15;
            const int which = ncol >> 11;
            const int oo = ncol & 2047;
            const int head = oo >> 7;
            const int d = oo & 127;
            _Float16* dst = (which == 0) ? Qo : (which == 1) ? Ko : Vo;
            const float scl = (which == 0) ? 0.08838834764831845f : 1.0f;
            #pragma unroll
            for (int i = 0; i < 4; ++i) {
                #pragma unroll
                for (int r = 0; r < 4; ++r) {
                    const int m = m0 + wr * 64 + i * 16 + lq * 4 + r;
                    const int b = m >> 11, tt = m & 2047;
                    dst[((size_t)(b * NH + head) * TSEQ + tt) * HD + d] =
                        (_Float16)(acc[i][j][r] * scl);
                }
            }
        }
    } else {
        #pragma unroll
        for (int i = 0; i < 4; ++i)
            #pragma unroll
            for (int j = 0; j < 4; ++j)
                #pragma unroll
                for (int r = 0; r < 4; ++r) {
                    const int m = m0 + wr * 64 + i * 16 + lq * 4 + r;
                    const int n = n0 + wc * 64 + j * 16 + l15;
                    C[(size_t)m * HID + n] = acc[i][j][r];
                }
    }
}

// ---- causal flash attention v4 ----
// 512 blocks x 4 waves (256 thr), QBLK=64 (16 rows/wave), KVBLK=64.
// Triangle pairs (31-p, p): uniform 33 kv-tile-units/block; 2 blocks/CU (72KB LDS).
// Sum-reduce via ones-MFMA (osum frag). Lazy local-max (no shuffles steady-state).
__global__ __launch_bounds__(256)
void attn_fwd(const _Float16* __restrict__ Q, const _Float16* __restrict__ K,
              const _Float16* __restrict__ V, _Float16* __restrict__ O) {
    __shared__ __align__(16) char Ks[2][64 * 256];   // [64][128] f16, swizzled
    __shared__ __align__(16) char Vt[2][128 * 128];  // [128][64] f16 (V^T), swizzled
    __shared__ __align__(16) char Ps[4][2048];       // per-wave [16][64] f16 P

    const int tid  = threadIdx.x;
    const int lane = tid & 63;
    const int w    = tid >> 6;      // 0..3
    const int l15  = lane & 15;
    const int lq   = lane >> 4;

    const int bh   = (int)blockIdx.x & 31;   // same-bh blocks share XCD (bid&7=bh&7)
    const int pair = (int)blockIdx.x >> 5;   // 0..15
    const int b = bh >> 4, h = bh & 15;

    const size_t base = (size_t)bh * TSEQ * HD;
    const _Float16* Qp = Q + base;
    const _Float16* Kp = K + base;
    const _Float16* Vp = V + base;

    const f16x8 ones = { (_Float16)1.f, (_Float16)1.f, (_Float16)1.f, (_Float16)1.f,
                         (_Float16)1.f, (_Float16)1.f, (_Float16)1.f, (_Float16)1.f };

    uint4 vv[4];
    auto loadV = [&](int t) {   // row = tid&63; wave w owns d-chunks w*4+it
        const int row = tid & 63;
        #pragma unroll
        for (int it = 0; it < 4; ++it) {
            const int c8 = w * 4 + it;
            vv[it] = *(const uint4*)(Vp + (size_t)(t * 64 + row) * HD + c8 * 8);
        }
    };
    auto stageK = [&](int t, int buf) {
        #pragma unroll
        for (int it = 0; it < 4; ++it) {
            const int slot = it * 256 + tid;
            const int row = slot >> 4, c16 = slot & 15;
            const int srcb = c16 ^ (row & 7);
            async_copy16(Kp + (size_t)(t * 64 + row) * HD + srcb * 8, Ks[buf] + slot * 16);
        }
    };
    auto writeV = [&](int buf) {   // ushort stores at d*128 + row*2: 2-way, free
        const int row = tid & 63;
        #pragma unroll
        for (int it = 0; it < 4; ++it) {
            const int c8 = w * 4 + it;
            const uint32_t wrd[4] = {vv[it].x, vv[it].y, vv[it].z, vv[it].w};
            #pragma unroll
            for (int p2 = 0; p2 < 4; ++p2) {
                const int d0 = c8 * 8 + p2 * 2, d1 = d0 + 1;
                int b0 = d0 * 128 + row * 2; b0 ^= (d0 & 7) << 4;
                int b1 = d1 * 128 + row * 2; b1 ^= (d1 & 7) << 4;
                *(ushort_t*)(Vt[buf] + b0) = (ushort_t)(wrd[p2] & 0xffffu);
                *(ushort_t*)(Vt[buf] + b1) = (ushort_t)(wrd[p2] >> 16);
            }
        }
    };

    char* Pb = Ps[w];

    for (int phase = 0; phase < 2; ++phase) {
        const int qt = phase ? pair : (31 - pair);
        const int q0 = qt * 64;
        const int NT = qt + 1;

        if (phase) __syncthreads();   // LDS reuse guard across phases

        const int qrow = q0 + w * 16 + l15;
        f16x8 qf[4];
        #pragma unroll
        for (int ks = 0; ks < 4; ++ks)
            qf[ks] = *(const f16x8*)(Qp + (size_t)qrow * HD + ks * 32 + lq * 8);

        f32x4 o[8] = {};
        f32x4 osum = {};              // running sum_kv P (ones-MFMA), rescaled with o
        float m_run[4];
        #pragma unroll
        for (int r = 0; r < 4; ++r) m_run[r] = -1e30f;

        loadV(0);
        stageK(0, 0);

        int cur = 0;
        for (int t = 0; t < NT; ++t) {
            writeV(cur);
            __syncthreads();
            if (t + 1 < NT) {
                loadV(t + 1);
                stageK(t + 1, cur ^ 1);
            }

            const int kv0 = t * 64;
            // S = Q K^T
            f32x4 s[4] = {};
            __builtin_amdgcn_s_setprio(1);
            #pragma unroll
            for (int ks = 0; ks < 4; ++ks) {
                #pragma unroll
                for (int nf = 0; nf < 4; ++nf) {
                    const int r   = nf * 16 + l15;
                    const int blk = (ks * 4 + lq) ^ (r & 7);
                    const f16x8 kf = *(const f16x8*)(Ks[cur] + r * 256 + blk * 16);
                    s[nf] = mfma16(qf[ks], kf, s[nf]);
                }
            }
            __builtin_amdgcn_s_setprio(0);

            if (kv0 + 63 > q0 + w * 16) {   // diagonal-crossing for this wave
                #pragma unroll
                for (int nf = 0; nf < 4; ++nf) {
                    const int kvp = kv0 + nf * 16 + l15;
                    #pragma unroll
                    for (int r = 0; r < 4; ++r)
                        if (kvp > q0 + w * 16 + lq * 4 + r) s[nf][r] = -1e30f;
                }
            }

            // lazy max: local (per-lane) check only; full reduce when triggered
            bool need = false;
            #pragma unroll
            for (int r = 0; r < 4; ++r) {
                const float v = fmaxf(fmaxf(s[0][r], s[1][r]), fmaxf(s[2][r], s[3][r]));
                need = need || (v > m_run[r] + 5.0f);
            }
            if (__any(need)) {
                float alpha[4];
                #pragma unroll
                for (int r = 0; r < 4; ++r) {
                    float v = fmaxf(fmaxf(s[0][r], s[1][r]), fmaxf(s[2][r], s[3][r]));
                    v = fmaxf(v, __shfl_xor(v, 1));
                    v = fmaxf(v, __shfl_xor(v, 2));
                    v = fmaxf(v, __shfl_xor(v, 4));
                    v = fmaxf(v, __shfl_xor(v, 8));
                    const float mn = fmaxf(m_run[r], v);
                    alpha[r] = __builtin_exp2f((m_run[r] - mn) * LOG2E);
                    m_run[r] = mn;
                }
                #pragma unroll
                for (int df = 0; df < 8; ++df)
                    #pragma unroll
                    for (int r = 0; r < 4; ++r)
                        o[df][r] *= alpha[r];
                #pragma unroll
                for (int r = 0; r < 4; ++r) osum[r] *= alpha[r];
            }

            // P = exp(S - m), store to wave-private LDS (f16)
            #pragma unroll
            for (int nf = 0; nf < 4; ++nf) {
                #pragma unroll
                for (int r = 0; r < 4; ++r) {
                    const float p = __builtin_exp2f((s[nf][r] - m_run[r]) * LOG2E);
                    const int qp = lq * 4 + r;
                    int byt = qp * 128 + (nf * 16 + l15) * 2;
                    byt ^= (qp & 7) << 4;
                    union { _Float16 hf; ushort_t u; } cv;
                    cv.hf = (_Float16)p;
                    *(ushort_t*)(Pb + byt) = cv.u;   // wave-private, in-order LDS
                }
            }

            // O += P @ V ; osum += P @ 1 (sum-reduce via MFMA)
            __builtin_amdgcn_s_setprio(1);
            #pragma unroll
            for (int ks2 = 0; ks2 < 2; ++ks2) {
                const int pblk = (ks2 * 4 + lq) ^ (l15 & 7);
                const f16x8 pf = *(const f16x8*)(Pb + l15 * 128 + pblk * 16);
                #pragma unroll
                for (int df = 0; df < 8; ++df) {
                    const int vr   = df * 16 + l15;
                    const int vblk = (ks2 * 4 + lq) ^ (vr & 7);
                    const f16x8 vf = *(const f16x8*)(Vt[cur] + vr * 128 + vblk * 16);
                    o[df] = mfma16(pf, vf, o[df]);
                }
                osum = mfma16(pf, ones, osum);
            }
            __builtin_amdgcn_s_setprio(0);
            cur ^= 1;
        }

        float rl[4];
        #pragma unroll
        for (int r = 0; r < 4; ++r) rl[r] = 1.0f / osum[r];
        #pragma unroll
        for (int df = 0; df < 8; ++df) {
            #pragma unroll
            for (int r = 0; r < 4; ++r) {
                const int qg = q0 + w * 16 + lq * 4 + r;
                const int dg = df * 16 + l15;
                O[((size_t)(b * TSEQ + qg)) * HID + h * HD + dg] =
                    (_Float16)(o[df][r] * rl[r]);
            }
        }
    }
}

extern "C" void kernel_launch(void* const* d_in, const int* in_sizes, int n_in,
                              void* d_out, int out_size, void* d_ws, size_t ws_size,
                              hipStream_t stream) {
    (void)in_sizes; (void)n_in; (void)out_size; (void)ws_size;
    const float* hs   = (const float*)d_in[0];
    const float* wqkv = (const float*)d_in[1];
    const float* wout = (const float*)d_in[2];

    char* ws = (char*)d_ws;
    size_t off = 0;
    _Float16* hs_h   = (_Float16*)(ws + off); off += (size_t)BATCH * TSEQ * HID * 2;
    _Float16* wqkv_h = (_Float16*)(ws + off); off += (size_t)3 * HID * HID * 2;
    _Float16* wout_h = (_Float16*)(ws + off); off += (size_t)HID * HID * 2;
    _Float16* Qh     = (_Float16*)(ws + off); off += (size_t)BATCH * NH * TSEQ * HD * 2;
    _Float16* Kh     = (_Float16*)(ws + off); off += (size_t)BATCH * NH * TSEQ * HD * 2;
    _Float16* Vh     = (_Float16*)(ws + off); off += (size_t)BATCH * NH * TSEQ * HD * 2;
    _Float16* At     = (_Float16*)(ws + off); off += (size_t)BATCH * TSEQ * HID * 2;

    const int n4_hs   = BATCH * TSEQ * HID / 4;
    const int n4_wqkv = 3 * HID * HID / 4;
    const int n4_wout = HID * HID / 4;
    cast_f32_f16<<<dim3((n4_hs   + 255) / 256), dim3(256), 0, stream>>>((const float4*)hs,   (f16x4*)hs_h,   n4_hs);
    cast_f32_f16<<<dim3((n4_wqkv + 255) / 256), dim3(256), 0, stream>>>((const float4*)wqkv, (f16x4*)wqkv_h, n4_wqkv);
    cast_f32_f16<<<dim3((n4_wout + 255) / 256), dim3(256), 0, stream>>>((const float4*)wout, (f16x4*)wout_h, n4_wout);

    gemm_bt<0><<<dim3(768), dim3(512), 0, stream>>>(
        hs_h, wqkv_h, nullptr, Qh, Kh, Vh, 48);

    attn_fwd<<<dim3(512), dim3(256), 0, stream>>>(Qh, Kh, Vh, At);

    gemm_bt<1><<<dim3(256), dim3(512), 0, stream>>>(
        At, wout_h, (float*)d_out, nullptr, nullptr, nullptr, 16);
}